// Round 1
// baseline (3288.060 us; speedup 1.0000x reference)
//
#include <hip/hip_runtime.h>
#include <math.h>

// Problem constants (from reference)
#define B_   8
#define T_   128
#define E_   256
#define H_   512
#define G_   2048
#define NWG  256           // 1 WG per CU (160KB LDS), all co-resident
#define NTHR 512           // 8 waves

typedef unsigned int u32;

// ---------------------------------------------------------------------------
// ALGEBRA (unchanged): softmax sums to 1 over t and h_shared is t-invariant =>
// Rt == h_last; attention path dead. Batches independent -> 8 rings of 32 WGs
// (ring = blockIdx&7 = XCD typ., slot = blockIdx>>3 owns h-cols 16s..16s+15).
// Exchange: img[gen&1][b][512] floats, mantissa-LSB parity tag (gen>>1)&1.
//
// R9 STRUCTURAL CHANGE (this round): ZERO barriers in the recurrence loops.
// Old structure had 2x __syncthreads + part[] LDS round-trip + wave0-only
// finalize per step -> each step was a ring-wide barrier (max over 32 slots,
// ~5000 cy/step measured, VALUBusy 22%). Now each WAVE is a self-contained
// pipeline: it polls all 512 h floats itself (8 coalesced dwords/lane, all in
// flight) into a wave-PRIVATE LDS h buffer, k-split is INTRA-wave (kch=l>>3),
// reduction via 3 shfl_xor, gates per-wave (2 h-cols each), publish per-wave.
// Inter-wave/inter-WG sync is only the per-float tag protocol itself.
// No-lap still holds per wave: a wave publishes gen g+1 only after validating
// ALL of gen g, so observing g+1 valid everywhere => all g-reads retired =>
// overwriting g (gen g+2, opposite parity) is safe. Buffers: buf0 LSB=0,
// buf1 LSB=1 at init.
//
// LDS = Wl 128K (f32, XOR-swizzled c^((k>>4)&31): per-lane column reads of
// wreg would be 32-way conflicted in the linear layout) + Xl 16K (bf16,
// XP=128 with t^((c&31)<<1) swizzle for bank spread) + hbuf 8x512 f32 16K
// = exactly 160 KiB. Dot's LDS reads use a kch-rotation -> <=2-way (free).
// ---------------------------------------------------------------------------

__device__ __forceinline__ float sigf(float x) { return 1.0f / (1.0f + expf(-x)); }

__device__ __forceinline__ unsigned short f2bf(float x) {
  u32 u = __float_as_uint(x);
  u += 0x7fffu + ((u >> 16) & 1u);
  return (unsigned short)(u >> 16);
}
__device__ __forceinline__ float bf2f(unsigned short s) {
  return __uint_as_float(((u32)s) << 16);
}

// img: u32[2][8][512] = 32KB at ws start
__global__ void init_ws(u32* w) {
  int i = blockIdx.x * blockDim.x + threadIdx.x;
  if (i < 4096)      w[i] = 0u;   // buf0: tag 0
  else if (i < 8192) w[i] = 1u;   // buf1: tag 1
}

// LDS index swizzles (must be used consistently by all readers/writers)
__device__ __forceinline__ int wl_idx(int k, int c) { return k * 64 + (c ^ ((k >> 4) & 31)); }
__device__ __forceinline__ int xl_idx(int c, int t) { return c * T_ + (t ^ ((c & 31) << 1)); }

// Stage k-major slice: Wl[k][c] = W[k][(c>>4)*H + s*16 + (c&15)], k < rows
__device__ __forceinline__ void stage_W(const float* __restrict__ W, int rows,
                                        int s, float* __restrict__ Wl) {
  for (int idx = threadIdx.x; idx < rows * 64; idx += NTHR) {
    int k = idx >> 6, c = idx & 63;
    Wl[wl_idx(k, c)] = W[k * G_ + ((c >> 4) * H_ + s * 16 + (c & 15))];
  }
}

__attribute__((amdgpu_waves_per_eu(2)))
__global__ __launch_bounds__(NTHR, 1) void lstm_all(
    const int* __restrict__ tokens, const float* __restrict__ embed,
    const float* __restrict__ Wih_s, const float* __restrict__ Whh_s,
    const float* __restrict__ b_s,
    const float* __restrict__ Wih_t, const float* __restrict__ Whh_t,
    const float* __restrict__ Wmh_t, const float* __restrict__ b_t,
    float* __restrict__ out, u32* __restrict__ img) {
  __shared__ float Wl[H_ * 64];            // 128 KiB, k-major weight slice (swizzled)
  __shared__ unsigned short Xl[64 * T_];   // 16 KiB, bf16 X (swizzled)
  __shared__ float hbuf[8][H_];            // 16 KiB, per-WAVE private h copy

  const int tid = threadIdx.x;
  const int l   = tid & 63;                // lane
  const int wv  = tid >> 6;                // wave: owns h-cols {2wv, 2wv+1} (local)
  const int b   = blockIdx.x & 7;          // ring = batch (XCD-aligned typ.)
  const int s   = blockIdx.x >> 3;         // slot: h-cols 16s..16s+15
  const int kch = l >> 3;                  // k-chunk 0..7 (64 k each)
  const int cc  = ((l & 7) >> 1) * 16 + 2 * wv + (l & 1);  // this lane's gate col
  const int d   = l & 1;                   // h-col parity within wave

  float wreg[64];                          // pinned per-lane weight K-slice

  // ---- X phase: Xl[c][t] (bf16) = emb[b,t] @ Wih[:,col(c)] + bias[col(c)]
  auto computeX = [&](const float* __restrict__ Wih, const float* __restrict__ bias) {
    stage_W(Wih, E_, s, Wl);               // 256x64 into Wl (fits)
    __syncthreads();
    const int t = tid >> 2, grp = tid & 3; // grp = gate; 16 cols each
    const int tok = tokens[b * T_ + t];
    const float4* er = (const float4*)(embed + (size_t)tok * E_);
    float acc[16];
#pragma unroll
    for (int j = 0; j < 16; ++j) acc[j] = bias[grp * H_ + s * 16 + j];
    for (int e4 = 0; e4 < E_ / 4; ++e4) {
      float4 em = er[e4];
#pragma unroll
      for (int eo = 0; eo < 4; ++eo) {
        float ev = reinterpret_cast<const float*>(&em)[eo];
        const int k = e4 * 4 + eo;
#pragma unroll
        for (int j = 0; j < 16; ++j) acc[j] += ev * Wl[wl_idx(k, grp * 16 + j)];
      }
    }
#pragma unroll
    for (int j = 0; j < 16; ++j) Xl[xl_idx(grp * 16 + j, t)] = f2bf(acc[j]);
  };

  auto load_wreg = [&] {
#pragma unroll
    for (int kk = 0; kk < 64; ++kk) wreg[kk] = Wl[wl_idx(kch * 64 + kk, cc)];
#pragma unroll
    for (int kk = 0; kk < 64; ++kk) asm volatile("" : "+v"(wreg[kk]));  // pin
  };

  // Per-WAVE poll: lane l validates floats {q*64+l, q=0..7} of gen, stages to
  // hbuf[wv]. All 8 loads issued together; only failures retried. The poll IS
  // the data read (1 L2 hop, ring is XCD-local).
  auto poll_wave = [&](unsigned gen) {
    const u32 par = (gen >> 1) & 1u;
    const u32* base = img + (gen & 1u) * 4096 + b * H_;
    u32 vals[8];
    u32 pending = 0xffu;
    while (pending) {
#pragma unroll
      for (int q = 0; q < 8; ++q) {
        if (pending & (1u << q)) {
          u32 u = __hip_atomic_load(base + q * 64 + l, __ATOMIC_RELAXED,
                                    __HIP_MEMORY_SCOPE_AGENT);
          if ((u & 1u) == par) { vals[q] = u; pending &= ~(1u << q); }
        }
      }
      if (pending) __builtin_amdgcn_s_sleep(1);
    }
#pragma unroll
    for (int q = 0; q < 8; ++q)
      hbuf[wv][q * 64 + l] = __uint_as_float(vals[q]);  // tag bit kept (1 ulp)
  };

  // Full dot for this lane's col: 64 FMAs over its k-chunk (kch-rotated LDS
  // reads: <=2-way bank aliasing = free), then 3 shfl_xor over the 8 chunks.
  auto do_dot = [&]() -> float {
    float a0 = 0.f, a1 = 0.f, a2 = 0.f, a3 = 0.f;
    const float4* h4 = (const float4*)(&hbuf[wv][kch * 64]);
#pragma unroll
    for (int i = 0; i < 16; ++i) {
      const int q = (i + 2 * kch) & 15;    // rotation de-conflicts banks
      float4 hv = h4[q];
      a0 += hv.x * wreg[q * 4 + 0];
      a1 += hv.y * wreg[q * 4 + 1];
      a2 += hv.z * wreg[q * 4 + 2];
      a3 += hv.w * wreg[q * 4 + 3];
    }
    float sum = (a0 + a1) + (a2 + a3);
    sum += __shfl_xor(sum, 8);
    sum += __shfl_xor(sum, 16);
    sum += __shfl_xor(sum, 32);
    return sum;                            // full pre-dot for col cc, all lanes
  };

  // ---------------- Phase A1 + shared weights
  computeX(Wih_s, b_s);
  __syncthreads();
  stage_W(Whh_s, H_, s, Wl);
  __syncthreads();
  load_wreg();

  float c_reg = 0.f, Mreg = 0.f;

  // ---------------- Phase B: shared LSTM; publishes gens 1..128. NO barriers.
  for (int t = 0; t < T_; ++t) {
    float pre = 0.f;
    if (t > 0) { poll_wave((unsigned)t); pre = do_dot(); }
    if (l < 8) pre += bf2f(Xl[xl_idx(cc, t)]);   // only shfl sources need X
    float gi = __shfl(pre, d),     gf = __shfl(pre, 2 + d),
          gg = __shfl(pre, 4 + d), go = __shfl(pre, 6 + d);
    float cn = sigf(gf) * c_reg + sigf(gi) * tanhf(gg);
    float hn = sigf(go) * tanhf(cn);
    c_reg = cn;
    if (l < 2) {                             // wave owns h-cols s*16+2wv+{0,1}
      const unsigned gw = (unsigned)t + 1u;
      u32 hb = (__float_as_uint(hn) & ~1u) | ((gw >> 1) & 1u);
      __hip_atomic_store(img + (gw & 1u) * 4096 + b * H_ + s * 16 + 2 * wv + l, hb,
                         __ATOMIC_RELAXED, __HIP_MEMORY_SCOPE_AGENT);
    }
  }

  // ---------------- M = h_last @ Wmh_t (consume gen 128)
  __syncthreads();
  stage_W(Wmh_t, H_, s, Wl);
  __syncthreads();
  load_wreg();
  poll_wave(128u);
  Mreg = do_dot();                           // M for col cc (consistent replicas)

  // ---------------- Phase A2 + task weights
  __syncthreads();
  computeX(Wih_t, b_t);
  __syncthreads();
  stage_W(Whh_t, H_, s, Wl);
  __syncthreads();
  load_wreg();

  // ---------------- Phase C: task LSTM; gens 129..255; out every step
  c_reg = 0.f;
  for (int t = 0; t < T_; ++t) {
    float pre = 0.f;
    if (t > 0) { poll_wave(128u + (unsigned)t); pre = do_dot(); }
    if (l < 8) pre += bf2f(Xl[xl_idx(cc, t)]) + Mreg;
    float gi = __shfl(pre, d),     gf = __shfl(pre, 2 + d),
          gg = __shfl(pre, 4 + d), go = __shfl(pre, 6 + d);
    float cn = sigf(gf) * c_reg + sigf(gi) * tanhf(gg);
    float hn = sigf(go) * tanhf(cn);
    c_reg = cn;
    if (l < 2) {
      out[b * (T_ * H_) + t * H_ + s * 16 + 2 * wv + l] = hn;
      if (t < T_ - 1) {
        const unsigned gw = 129u + (unsigned)t;
        u32 hb = (__float_as_uint(hn) & ~1u) | ((gw >> 1) & 1u);
        __hip_atomic_store(img + (gw & 1u) * 4096 + b * H_ + s * 16 + 2 * wv + l, hb,
                           __ATOMIC_RELAXED, __HIP_MEMORY_SCOPE_AGENT);
      }
    }
  }
}

extern "C" void kernel_launch(void* const* d_in, const int* in_sizes, int n_in,
                              void* d_out, int out_size, void* d_ws, size_t ws_size,
                              hipStream_t stream) {
  const int*   tokens = (const int*)d_in[0];
  // d_in[1] = TASK (unused)
  const float* embed  = (const float*)d_in[2];
  const float* Wih_s  = (const float*)d_in[3];
  const float* Whh_s  = (const float*)d_in[4];
  const float* b_s    = (const float*)d_in[5];
  // d_in[6..9] = Ws_w, Ws_b, Us_w, Us_b -> dead (attention collapses)
  const float* Wih_t  = (const float*)d_in[10];
  const float* Whh_t  = (const float*)d_in[11];
  const float* Wmh_t  = (const float*)d_in[12];
  const float* b_t    = (const float*)d_in[13];
  float* out = (float*)d_out;
  u32*   img = (u32*)d_ws;

  hipLaunchKernelGGL(init_ws, dim3(8), dim3(1024), 0, stream, img);
  hipLaunchKernelGGL(lstm_all, dim3(NWG), dim3(NTHR), 0, stream,
                     tokens, embed, Wih_s, Whh_s, b_s,
                     Wih_t, Whh_t, Wmh_t, b_t, out, img);
}

// Round 5
// 2380.858 us; speedup vs baseline: 1.3810x; 1.3810x over previous
//
#include <hip/hip_runtime.h>
#include <math.h>

// Problem constants (from reference)
#define B_   8
#define T_   128
#define E_   256
#define H_   512
#define G_   2048
#define NWG  256           // 1 WG per CU (148KB LDS), all co-resident (R8-proven)
#define NTHR 512           // 8 waves

typedef unsigned int u32;
typedef unsigned long long u64;

// ---------------------------------------------------------------------------
// ALGEBRA (unchanged): softmax sums to 1 over t and h_shared is t-invariant =>
// Rt == h_last; attention path dead. Batches independent -> 8 rings of 32 WGs
// (ring = blockIdx&7, slot = blockIdx>>3 owns h-cols 16s..16s+15).
//
// R13: R11/R12 falsified "plain store + sc0 load meet coherently at the XCD
// L2" (both runs wrong; fallback path == R8's proven agent transport, so the
// failure localizes to the pure-L2 path). New transport is self-verifying:
//  - 8B records (value | gen<<32): poll accepts ONLY exact gen match (+ LSB
//    parity in value as anti-tear). Stale transport => retry, NEVER silent
//    corruption (R12's 4-gen parity window allowed false positives).
//  - DUAL publish: L2 mailbox (global_store_dwordx2 sc0) AND MALL mailbox
//    (__hip_atomic_store agent — R8-proven guaranteed visibility).
//  - Adaptive poll: try L2 mailbox 32 spins; timeout -> MALL mailbox
//    (guaranteed); after MALL delivery, re-probe L2 once — if it still lags
//    the delivered gen, classify L2 dead (per-thread) and skip forever.
//    Transients don't kill the fast path; a dead path costs once.
// Correctness rests only on the agent path + exact-gen matching.
//
// Step structure (R12, logic verified): 1 barrier/step; each thread polls ITS
// OWN float (1x traffic) into gen-parity double-buffered hb[2][512];
// __syncthreads; per-wave intra-wave dot (kch=l>>3 over shared hb + 3
// shfl_xor); per-wave gates via 4 shfl; 2 lanes/wave publish. No-lap: a WG
// publishes gen g+1 only after its barrier confirmed all 512 of gen g
// validated; inductively nobody overwrites a gen still being read. hb reuse
// safe: poll writes of g+1 target hb[(g+1)&1]; stragglers read hb[g&1];
// barrier(g) separates dot(g-1) reads from poll(g+1) writes (same parity).
//
// ws: u64 L2-mailbox[2][8][512] at 0 (64KB) + u64 MALL-mailbox same (64KB).
// init: gen halves 0xFFFFFFFF (never a real gen; publishes use 1..255).
// Watchdog: finite MALL retries -> wedge = wrong-but-diagnosable, not a hang.
//
// LDS = Wl 128K (f32, XOR-swizzle c^((k>>4)&31)) + Xl 16K (bf16, swizzled)
// + hb 4K = 148 KiB.
// ---------------------------------------------------------------------------

__device__ __forceinline__ float sigf(float x) { return 1.0f / (1.0f + expf(-x)); }

__device__ __forceinline__ unsigned short f2bf(float x) {
  u32 u = __float_as_uint(x);
  u += 0x7fffu + ((u >> 16) & 1u);
  return (unsigned short)(u >> 16);
}
__device__ __forceinline__ float bf2f(unsigned short s) {
  return __uint_as_float(((u32)s) << 16);
}

// ws: 32768 u32 (two u64[2][8][512] mailboxes). Fill with 0xFFFFFFFF:
// every record reads as gen 0xFFFFFFFF -> no poll can match.
__global__ void init_ws(u32* w) {
  int i = blockIdx.x * blockDim.x + threadIdx.x;
  if (i < 32768) w[i] = 0xFFFFFFFFu;
}

// LDS index swizzles (used consistently by all readers/writers)
__device__ __forceinline__ int wl_idx(int k, int c) { return k * 64 + (c ^ ((k >> 4) & 31)); }
__device__ __forceinline__ int xl_idx(int c, int t) { return c * T_ + (t ^ ((c & 31) << 1)); }

// Stage k-major slice: Wl[k][c] = W[k][(c>>4)*H + s*16 + (c&15)], k < rows
__device__ __forceinline__ void stage_W(const float* __restrict__ W, int rows,
                                        int s, float* __restrict__ Wl) {
  for (int idx = threadIdx.x; idx < rows * 64; idx += NTHR) {
    int k = idx >> 6, c = idx & 63;
    Wl[wl_idx(k, c)] = W[k * G_ + ((c >> 4) * H_ + s * 16 + (c & 15))];
  }
}

__attribute__((amdgpu_waves_per_eu(2)))
__global__ __launch_bounds__(NTHR, 1) void lstm_all(
    const int* __restrict__ tokens, const float* __restrict__ embed,
    const float* __restrict__ Wih_s, const float* __restrict__ Whh_s,
    const float* __restrict__ b_s,
    const float* __restrict__ Wih_t, const float* __restrict__ Whh_t,
    const float* __restrict__ Wmh_t, const float* __restrict__ b_t,
    float* __restrict__ out, u64* __restrict__ ws) {
  __shared__ float Wl[H_ * 64];            // 128 KiB, k-major weight slice (swizzled)
  __shared__ unsigned short Xl[64 * T_];   // 16 KiB, bf16 X (swizzled)
  __shared__ float hb[2][H_];              // 4 KiB, gen-parity double-buffered h

  u64* __restrict__ imgL2   = ws;          // opportunistic (sc0 / L2)
  u64* __restrict__ imgMall = ws + 8192;   // guaranteed (agent scope)

  const int tid = threadIdx.x;
  const int l   = tid & 63;                // lane
  const int wv  = tid >> 6;                // wave: owns h-cols {2wv, 2wv+1} (local)
  const int b   = blockIdx.x & 7;          // ring = batch (guaranteed coverage)
  const int s   = blockIdx.x >> 3;         // slot: h-cols 16s..16s+15
  const int kch = l >> 3;                  // k-chunk 0..7 (64 k each)
  const int cc  = ((l & 7) >> 1) * 16 + 2 * wv + (l & 1);  // this lane's gate col
  const int d   = l & 1;                   // h-col parity within wave
  const unsigned bH = (unsigned)(b * H_);

  int  wd   = 1 << 20;                     // watchdog: MALL retries/thread
  bool l2ok = true;                        // per-thread fast-path health
  float wreg[64];                          // pinned per-lane weight K-slice

  // ---- X phase: Xl[c][t] (bf16) = emb[b,t] @ Wih[:,col(c)] + bias[col(c)]
  auto computeX = [&](const float* __restrict__ Wih, const float* __restrict__ bias) {
    stage_W(Wih, E_, s, Wl);               // 256x64 into Wl (fits)
    __syncthreads();
    const int t = tid >> 2, grp = tid & 3; // grp = gate; 16 cols each
    const int tok = tokens[b * T_ + t];
    const float4* er = (const float4*)(embed + (size_t)tok * E_);
    float acc[16];
#pragma unroll
    for (int j = 0; j < 16; ++j) acc[j] = bias[grp * H_ + s * 16 + j];
    for (int e4 = 0; e4 < E_ / 4; ++e4) {
      float4 em = er[e4];
#pragma unroll
      for (int eo = 0; eo < 4; ++eo) {
        float ev = reinterpret_cast<const float*>(&em)[eo];
        const int k = e4 * 4 + eo;
#pragma unroll
        for (int j = 0; j < 16; ++j) acc[j] += ev * Wl[wl_idx(k, grp * 16 + j)];
      }
    }
#pragma unroll
    for (int j = 0; j < 16; ++j) Xl[xl_idx(grp * 16 + j, t)] = f2bf(acc[j]);
  };

  auto load_wreg = [&] {
#pragma unroll
    for (int kk = 0; kk < 64; ++kk) wreg[kk] = Wl[wl_idx(kch * 64 + kk, cc)];
#pragma unroll
    for (int kk = 0; kk < 64; ++kk) asm volatile("" : "+v"(wreg[kk]));  // pin
  };

  // Per-THREAD poll of OWN record. Accept iff gen matches exactly AND value
  // LSB parity matches (anti-tear). L2 mailbox first (32 spins), then MALL.
  auto poll_own = [&](unsigned gen) {
    const u32 pbuf = gen & 1u, par = (gen >> 1) & 1u;
    const unsigned idx = pbuf * 4096u + bH + (unsigned)tid;
    u32 val = 0u;
    bool got = false;
    if (l2ok) {
      const u64* p = imgL2 + idx;
      for (int i = 0; i < 32 && !got; ++i) {
        u64 v;
        asm volatile("global_load_dwordx2 %0, %1, off sc0\n\ts_waitcnt vmcnt(0)"
                     : "=v"(v) : "v"(p) : "memory");
        if ((u32)(v >> 32) == gen && (((u32)v) & 1u) == par) { val = (u32)v; got = true; }
      }
    }
    if (!got) {
      const u64* q = imgMall + idx;
      for (;;) {
        u64 v = __hip_atomic_load(q, __ATOMIC_RELAXED, __HIP_MEMORY_SCOPE_AGENT);
        if ((u32)(v >> 32) == gen && (((u32)v) & 1u) == par) { val = (u32)v; break; }
        if (--wd < 0) break;               // fail fast, not hang
        __builtin_amdgcn_s_sleep(1);
      }
      if (l2ok) {                          // classify: transient vs dead L2 path
        u64 v; const u64* p = imgL2 + idx;
        asm volatile("global_load_dwordx2 %0, %1, off sc0\n\ts_waitcnt vmcnt(0)"
                     : "=v"(v) : "v"(p) : "memory");
        if ((u32)(v >> 32) != gen) l2ok = false;   // MALL delivered, L2 lags => dead
      }
    }
    hb[pbuf][tid] = __uint_as_float(val);  // tag bit kept (1 ulp, harmless)
  };

  // Dual publish of one record: opportunistic L2 store + guaranteed agent store.
  auto publish = [&](unsigned gen, int fi, float hn) {
    u32 val = (__float_as_uint(hn) & ~1u) | ((gen >> 1) & 1u);
    u64 pack = ((u64)gen << 32) | (u64)val;
    const unsigned idx = (gen & 1u) * 4096u + bH + (unsigned)fi;
    u64* p = imgL2 + idx;
    asm volatile("global_store_dwordx2 %0, %1, off sc0"
                 :: "v"(p), "v"(pack) : "memory");
    __hip_atomic_store(imgMall + idx, pack, __ATOMIC_RELAXED,
                       __HIP_MEMORY_SCOPE_AGENT);
  };

  // Full dot for this lane's col from SHARED hb[par]: 64 FMAs over its
  // k-chunk (kch-rotated reads: 2-way bank aliasing = free; same-kch lanes
  // broadcast), then 3 shfl_xor over the 8 chunks.
  auto do_dot = [&](unsigned par) -> float {
    float a0 = 0.f, a1 = 0.f, a2 = 0.f, a3 = 0.f;
    const float4* h4 = (const float4*)(&hb[par][kch * 64]);
#pragma unroll
    for (int i = 0; i < 16; ++i) {
      const int q = (i + 2 * kch) & 15;    // rotation de-conflicts banks
      float4 hv = h4[q];
      a0 += hv.x * wreg[q * 4 + 0];
      a1 += hv.y * wreg[q * 4 + 1];
      a2 += hv.z * wreg[q * 4 + 2];
      a3 += hv.w * wreg[q * 4 + 3];
    }
    float sum = (a0 + a1) + (a2 + a3);
    sum += __shfl_xor(sum, 8);
    sum += __shfl_xor(sum, 16);
    sum += __shfl_xor(sum, 32);
    return sum;                            // full pre-dot for col cc, all lanes
  };

  // ---------------- Phase A1 + shared weights
  computeX(Wih_s, b_s);
  __syncthreads();
  stage_W(Whh_s, H_, s, Wl);
  __syncthreads();
  load_wreg();

  float c_reg = 0.f, Mreg = 0.f;

  // ---------------- Phase B: shared LSTM; publishes gens 1..128. 1 barrier/step.
  for (int t = 0; t < T_; ++t) {
    if (t > 0) poll_own((unsigned)t);
    __syncthreads();                       // hb[t&1] complete for all waves
    float pre = (t > 0) ? do_dot((unsigned)t & 1u) : 0.f;
    if (l < 8) pre += bf2f(Xl[xl_idx(cc, t)]);   // only shfl sources need X
    float gi = __shfl(pre, d),     gf = __shfl(pre, 2 + d),
          gg = __shfl(pre, 4 + d), go = __shfl(pre, 6 + d);
    float cn = sigf(gf) * c_reg + sigf(gi) * tanhf(gg);
    float hn = sigf(go) * tanhf(cn);
    c_reg = cn;
    if (l < 2)                             // wave owns h-cols s*16+2wv+{0,1}
      publish((unsigned)t + 1u, s * 16 + 2 * wv + l, hn);
  }

  // ---------------- M = h_last @ Wmh_t (consume gen 128)
  __syncthreads();
  stage_W(Wmh_t, H_, s, Wl);
  __syncthreads();
  load_wreg();
  poll_own(128u);
  __syncthreads();
  Mreg = do_dot(0u);                       // gen 128 parity buffer

  // ---------------- Phase A2 + task weights
  __syncthreads();
  computeX(Wih_t, b_t);
  __syncthreads();
  stage_W(Whh_t, H_, s, Wl);
  __syncthreads();
  load_wreg();

  // ---------------- Phase C: task LSTM; gens 129..255; out every step
  c_reg = 0.f;
  for (int t = 0; t < T_; ++t) {
    if (t > 0) poll_own(128u + (unsigned)t);
    __syncthreads();
    float pre = (t > 0) ? do_dot((128u + (unsigned)t) & 1u) : 0.f;
    if (l < 8) pre += bf2f(Xl[xl_idx(cc, t)]) + Mreg;
    float gi = __shfl(pre, d),     gf = __shfl(pre, 2 + d),
          gg = __shfl(pre, 4 + d), go = __shfl(pre, 6 + d);
    float cn = sigf(gf) * c_reg + sigf(gi) * tanhf(gg);
    float hn = sigf(go) * tanhf(cn);
    c_reg = cn;
    if (l < 2) {
      out[b * (T_ * H_) + t * H_ + s * 16 + 2 * wv + l] = hn;
      if (t < T_ - 1)
        publish(129u + (unsigned)t, s * 16 + 2 * wv + l, hn);
    }
  }
}

extern "C" void kernel_launch(void* const* d_in, const int* in_sizes, int n_in,
                              void* d_out, int out_size, void* d_ws, size_t ws_size,
                              hipStream_t stream) {
  const int*   tokens = (const int*)d_in[0];
  // d_in[1] = TASK (unused)
  const float* embed  = (const float*)d_in[2];
  const float* Wih_s  = (const float*)d_in[3];
  const float* Whh_s  = (const float*)d_in[4];
  const float* b_s    = (const float*)d_in[5];
  // d_in[6..9] = Ws_w, Ws_b, Us_w, Us_b -> dead (attention collapses)
  const float* Wih_t  = (const float*)d_in[10];
  const float* Whh_t  = (const float*)d_in[11];
  const float* Wmh_t  = (const float*)d_in[12];
  const float* b_t    = (const float*)d_in[13];
  float* out = (float*)d_out;

  hipLaunchKernelGGL(init_ws, dim3(32), dim3(1024), 0, stream, (u32*)d_ws);
  hipLaunchKernelGGL(lstm_all, dim3(NWG), dim3(NTHR), 0, stream,
                     tokens, embed, Wih_s, Whh_s, b_s,
                     Wih_t, Whh_t, Wmh_t, b_t, out, (u64*)d_ws);
}

// Round 6
// 2246.428 us; speedup vs baseline: 1.4637x; 1.0598x over previous
//
#include <hip/hip_runtime.h>
#include <math.h>

// Problem constants (from reference)
#define B_   8
#define T_   128
#define E_   256
#define H_   512
#define G_   2048
#define NWG  256           // 1 WG per CU (148KB LDS), all co-resident (R8-proven)
#define NTHR 512           // 8 waves

typedef unsigned int u32;
typedef unsigned long long u64;

// ---------------------------------------------------------------------------
// ALGEBRA (unchanged): softmax sums to 1 over t and h_shared is t-invariant =>
// Rt == h_last; attention path dead. Batches independent -> 8 rings of 32 WGs
// (ring = blockIdx&7, slot = blockIdx>>3 owns h-cols 16s..16s+15).
//
// R14: transport = MALL-ONLY. Three-experiment conclusion: cross-CU
// store->sc0-load via the XCD L2 does NOT deliver promptly on gfx950 at HIP
// level (R12: multi-gen lag aliased the 2-bit parity tag -> corruption;
// R13: exact-gen tags made it correct but the 32-spin L2 probe burned 968MB
// of fabric fetches -> 2.4ms). Agent-scope (MALL) is the only transport that
// works; R8/R13 both prove it correct.
//
// Kept from R13 (PASSED, so math verified end-to-end):
//  - 8B records (value | gen<<32): poll accepts ONLY exact gen match (+ LSB
//    parity in value as anti-tear). Stale transport => retry, never corrupt.
//  - Step = ONE barrier: each thread polls ITS OWN record (1x traffic; R9's
//    8x redundant polling saturated MALL) into gen-parity double-buffered
//    hb[2][512]; __syncthreads; per-wave intra-wave dot (kch=l>>3 split over
//    shared hb + 3 shfl_xor); per-wave gates via 4 shfl; 2 lanes/wave
//    publish. vs R8 (540us): removes 1 barrier + part[] round-trip + wave0
//    serialized finalize from every step.
// No-lap: a WG publishes gen g+1 only after its barrier confirmed all 512 of
// gen g validated; inductively nobody overwrites a gen still being read.
// hb reuse safe: poll writes of g+1 target hb[(g+1)&1]; stragglers read
// hb[g&1]; the next barrier separates same-parity reuse.
//
// ws: u64 mailbox[2][8][512] (64KB). init: gen halves 0xFFFFFFFF (never a
// real gen; publishes use 1..255). Watchdog: finite retries -> wedge becomes
// wrong-but-diagnosable, not a hang.
//
// LDS = Wl 128K (f32, XOR-swizzle c^((k>>4)&31)) + Xl 16K (bf16, swizzled)
// + hb 4K = 148 KiB.
// ---------------------------------------------------------------------------

__device__ __forceinline__ float sigf(float x) { return 1.0f / (1.0f + expf(-x)); }

__device__ __forceinline__ unsigned short f2bf(float x) {
  u32 u = __float_as_uint(x);
  u += 0x7fffu + ((u >> 16) & 1u);
  return (unsigned short)(u >> 16);
}
__device__ __forceinline__ float bf2f(unsigned short s) {
  return __uint_as_float(((u32)s) << 16);
}

// ws: 8192 u64 mailbox. Fill with 0xFFFFFFFF dwords: every record reads as
// gen 0xFFFFFFFF -> no poll can match.
__global__ void init_ws(u32* w) {
  int i = blockIdx.x * blockDim.x + threadIdx.x;
  if (i < 16384) w[i] = 0xFFFFFFFFu;
}

// LDS index swizzles (used consistently by all readers/writers)
__device__ __forceinline__ int wl_idx(int k, int c) { return k * 64 + (c ^ ((k >> 4) & 31)); }
__device__ __forceinline__ int xl_idx(int c, int t) { return c * T_ + (t ^ ((c & 31) << 1)); }

// Stage k-major slice: Wl[k][c] = W[k][(c>>4)*H + s*16 + (c&15)], k < rows
__device__ __forceinline__ void stage_W(const float* __restrict__ W, int rows,
                                        int s, float* __restrict__ Wl) {
  for (int idx = threadIdx.x; idx < rows * 64; idx += NTHR) {
    int k = idx >> 6, c = idx & 63;
    Wl[wl_idx(k, c)] = W[k * G_ + ((c >> 4) * H_ + s * 16 + (c & 15))];
  }
}

__attribute__((amdgpu_waves_per_eu(2)))
__global__ __launch_bounds__(NTHR, 1) void lstm_all(
    const int* __restrict__ tokens, const float* __restrict__ embed,
    const float* __restrict__ Wih_s, const float* __restrict__ Whh_s,
    const float* __restrict__ b_s,
    const float* __restrict__ Wih_t, const float* __restrict__ Whh_t,
    const float* __restrict__ Wmh_t, const float* __restrict__ b_t,
    float* __restrict__ out, u64* __restrict__ img) {
  __shared__ float Wl[H_ * 64];            // 128 KiB, k-major weight slice (swizzled)
  __shared__ unsigned short Xl[64 * T_];   // 16 KiB, bf16 X (swizzled)
  __shared__ float hb[2][H_];              // 4 KiB, gen-parity double-buffered h

  const int tid = threadIdx.x;
  const int l   = tid & 63;                // lane
  const int wv  = tid >> 6;                // wave: owns h-cols {2wv, 2wv+1} (local)
  const int b   = blockIdx.x & 7;          // ring = batch (guaranteed coverage)
  const int s   = blockIdx.x >> 3;         // slot: h-cols 16s..16s+15
  const int kch = l >> 3;                  // k-chunk 0..7 (64 k each)
  const int cc  = ((l & 7) >> 1) * 16 + 2 * wv + (l & 1);  // this lane's gate col
  const int d   = l & 1;                   // h-col parity within wave
  const unsigned bH = (unsigned)(b * H_);

  int wd = 1 << 20;                        // watchdog: poll retries/thread
  float wreg[64];                          // pinned per-lane weight K-slice

  // ---- X phase: Xl[c][t] (bf16) = emb[b,t] @ Wih[:,col(c)] + bias[col(c)]
  auto computeX = [&](const float* __restrict__ Wih, const float* __restrict__ bias) {
    stage_W(Wih, E_, s, Wl);               // 256x64 into Wl (fits)
    __syncthreads();
    const int t = tid >> 2, grp = tid & 3; // grp = gate; 16 cols each
    const int tok = tokens[b * T_ + t];
    const float4* er = (const float4*)(embed + (size_t)tok * E_);
    float acc[16];
#pragma unroll
    for (int j = 0; j < 16; ++j) acc[j] = bias[grp * H_ + s * 16 + j];
    for (int e4 = 0; e4 < E_ / 4; ++e4) {
      float4 em = er[e4];
#pragma unroll
      for (int eo = 0; eo < 4; ++eo) {
        float ev = reinterpret_cast<const float*>(&em)[eo];
        const int k = e4 * 4 + eo;
#pragma unroll
        for (int j = 0; j < 16; ++j) acc[j] += ev * Wl[wl_idx(k, grp * 16 + j)];
      }
    }
#pragma unroll
    for (int j = 0; j < 16; ++j) Xl[xl_idx(grp * 16 + j, t)] = f2bf(acc[j]);
  };

  auto load_wreg = [&] {
#pragma unroll
    for (int kk = 0; kk < 64; ++kk) wreg[kk] = Wl[wl_idx(kch * 64 + kk, cc)];
#pragma unroll
    for (int kk = 0; kk < 64; ++kk) asm volatile("" : "+v"(wreg[kk]));  // pin
  };

  // Per-THREAD poll of OWN record via MALL (agent scope — the proven path).
  // Accept iff gen matches exactly AND value LSB parity matches (anti-tear).
  auto poll_own = [&](unsigned gen) {
    const u32 pbuf = gen & 1u, par = (gen >> 1) & 1u;
    const u64* q = img + pbuf * 4096u + bH + (unsigned)tid;
    u32 val = 0u;
    for (;;) {
      u64 v = __hip_atomic_load(q, __ATOMIC_RELAXED, __HIP_MEMORY_SCOPE_AGENT);
      if ((u32)(v >> 32) == gen && (((u32)v) & 1u) == par) { val = (u32)v; break; }
      if (--wd < 0) break;                 // fail fast, not hang
      __builtin_amdgcn_s_sleep(1);
    }
    hb[pbuf][tid] = __uint_as_float(val);  // tag bit kept (1 ulp, harmless)
  };

  // Publish one record to the MALL mailbox (agent scope).
  auto publish = [&](unsigned gen, int fi, float hn) {
    u32 val = (__float_as_uint(hn) & ~1u) | ((gen >> 1) & 1u);
    u64 pack = ((u64)gen << 32) | (u64)val;
    __hip_atomic_store(img + (gen & 1u) * 4096u + bH + (unsigned)fi, pack,
                       __ATOMIC_RELAXED, __HIP_MEMORY_SCOPE_AGENT);
  };

  // Full dot for this lane's col from SHARED hb[par]: 64 FMAs over its
  // k-chunk (kch-rotated reads: same-kch lanes broadcast; cross-group <=2-way
  // bank aliasing = free), then 3 shfl_xor over the 8 chunks.
  auto do_dot = [&](unsigned par) -> float {
    float a0 = 0.f, a1 = 0.f, a2 = 0.f, a3 = 0.f;
    const float4* h4 = (const float4*)(&hb[par][kch * 64]);
#pragma unroll
    for (int i = 0; i < 16; ++i) {
      const int q = (i + 2 * kch) & 15;    // rotation de-conflicts banks
      float4 hv = h4[q];
      a0 += hv.x * wreg[q * 4 + 0];
      a1 += hv.y * wreg[q * 4 + 1];
      a2 += hv.z * wreg[q * 4 + 2];
      a3 += hv.w * wreg[q * 4 + 3];
    }
    float sum = (a0 + a1) + (a2 + a3);
    sum += __shfl_xor(sum, 8);
    sum += __shfl_xor(sum, 16);
    sum += __shfl_xor(sum, 32);
    return sum;                            // full pre-dot for col cc, all lanes
  };

  // ---------------- Phase A1 + shared weights
  computeX(Wih_s, b_s);
  __syncthreads();
  stage_W(Whh_s, H_, s, Wl);
  __syncthreads();
  load_wreg();

  float c_reg = 0.f, Mreg = 0.f;

  // ---------------- Phase B: shared LSTM; publishes gens 1..128. 1 barrier/step.
  for (int t = 0; t < T_; ++t) {
    if (t > 0) poll_own((unsigned)t);
    __syncthreads();                       // hb[t&1] complete for all waves
    float pre = (t > 0) ? do_dot((unsigned)t & 1u) : 0.f;
    if (l < 8) pre += bf2f(Xl[xl_idx(cc, t)]);   // only shfl sources need X
    float gi = __shfl(pre, d),     gf = __shfl(pre, 2 + d),
          gg = __shfl(pre, 4 + d), go = __shfl(pre, 6 + d);
    float cn = sigf(gf) * c_reg + sigf(gi) * tanhf(gg);
    float hn = sigf(go) * tanhf(cn);
    c_reg = cn;
    if (l < 2)                             // wave owns h-cols s*16+2wv+{0,1}
      publish((unsigned)t + 1u, s * 16 + 2 * wv + l, hn);
  }

  // ---------------- M = h_last @ Wmh_t (consume gen 128)
  __syncthreads();
  stage_W(Wmh_t, H_, s, Wl);
  __syncthreads();
  load_wreg();
  poll_own(128u);
  __syncthreads();
  Mreg = do_dot(0u);                       // gen 128 parity buffer

  // ---------------- Phase A2 + task weights
  __syncthreads();
  computeX(Wih_t, b_t);
  __syncthreads();
  stage_W(Whh_t, H_, s, Wl);
  __syncthreads();
  load_wreg();

  // ---------------- Phase C: task LSTM; gens 129..255; out every step
  c_reg = 0.f;
  for (int t = 0; t < T_; ++t) {
    if (t > 0) poll_own(128u + (unsigned)t);
    __syncthreads();
    float pre = (t > 0) ? do_dot((128u + (unsigned)t) & 1u) : 0.f;
    if (l < 8) pre += bf2f(Xl[xl_idx(cc, t)]) + Mreg;
    float gi = __shfl(pre, d),     gf = __shfl(pre, 2 + d),
          gg = __shfl(pre, 4 + d), go = __shfl(pre, 6 + d);
    float cn = sigf(gf) * c_reg + sigf(gi) * tanhf(gg);
    float hn = sigf(go) * tanhf(cn);
    c_reg = cn;
    if (l < 2) {
      out[b * (T_ * H_) + t * H_ + s * 16 + 2 * wv + l] = hn;
      if (t < T_ - 1)
        publish(129u + (unsigned)t, s * 16 + 2 * wv + l, hn);
    }
  }
}

extern "C" void kernel_launch(void* const* d_in, const int* in_sizes, int n_in,
                              void* d_out, int out_size, void* d_ws, size_t ws_size,
                              hipStream_t stream) {
  const int*   tokens = (const int*)d_in[0];
  // d_in[1] = TASK (unused)
  const float* embed  = (const float*)d_in[2];
  const float* Wih_s  = (const float*)d_in[3];
  const float* Whh_s  = (const float*)d_in[4];
  const float* b_s    = (const float*)d_in[5];
  // d_in[6..9] = Ws_w, Ws_b, Us_w, Us_b -> dead (attention collapses)
  const float* Wih_t  = (const float*)d_in[10];
  const float* Whh_t  = (const float*)d_in[11];
  const float* Wmh_t  = (const float*)d_in[12];
  const float* b_t    = (const float*)d_in[13];
  float* out = (float*)d_out;

  hipLaunchKernelGGL(init_ws, dim3(16), dim3(1024), 0, stream, (u32*)d_ws);
  hipLaunchKernelGGL(lstm_all, dim3(NWG), dim3(NTHR), 0, stream,
                     tokens, embed, Wih_s, Whh_s, b_s,
                     Wih_t, Whh_t, Wmh_t, b_t, out, (u64*)d_ws);
}

// Round 7
// 1791.424 us; speedup vs baseline: 1.8354x; 1.2540x over previous
//
#include <hip/hip_runtime.h>
#include <math.h>

// Problem constants (from reference)
#define B_   8
#define T_   128
#define E_   256
#define H_   512
#define G_   2048
#define NWG  256           // 1 WG per CU (146KB LDS), all co-resident (R8-proven)
#define NTHR 512           // 8 waves

typedef unsigned int u32;

// ---------------------------------------------------------------------------
// ALGEBRA (unchanged): softmax sums to 1 over t and h_shared is t-invariant =>
// Rt == h_last; attention path dead. Batches independent -> 8 rings of 32 WGs
// (ring = blockIdx&7, slot = blockIdx>>3 owns h-cols 16s..16s+15).
//
// R15: transport = R8's EXACT scheme (the only one that ever hit 540us):
//  - 4B records, in-band mantissa-LSB parity tag (gen>>1)&1, buffer gen&1.
//  - per-thread poll of OWN float (1x traffic), agent scope (MALL).
//  - publish = ONE 16-lane 64B store by wave0. RULE (R9/R13/R14 lesson, each
//    violated it and ran 4-6x slower): one mailbox cache line must be written
//    by exactly ONE store instruction from ONE wave. Scattered partial-line
//    agent writes from multiple waves serialize at MALL (~4x step inflation
//    with 4 writers/line in R14).
// What changed vs R8 (the intra-WG schedule only):
//  - R8's serial wave0 finalize (8 part[] LDS reads + sum + libm gates,
//    ~300-600cy on the critical path each step) is replaced by R14's VERIFIED
//    distributed dot+gates: each wave computes its 2 h-cols via kch-split
//    over shared h_lds + 3 shfl_xor + 4 shfl gate gather, all 8 waves in
//    parallel; results drop into hOut[16]; barrier; wave0 single-store
//    publishes (and in phase C single-store writes out[]). part[] is gone.
//  - libm expf/tanhf -> __expf-based fast gates (v_exp_f32), clamped.
// Barriers per step: 2 (same as R8). Serial tail after last gate: LDS read
// + one store.
//
// No-lap (R8 argument): a WG publishes gen g+1 only after its barrier
// confirmed all 512 of gen g validated => everyone read g-1 => 2 buffers
// suffice; parity distinguishes g from g-2. init: buf0 LSB=0, buf1 LSB=1.
// Watchdog: finite poll retries -> wedge = wrong-but-diagnosable, not hang.
//
// LDS = Wl 128K (f32, XOR-swizzle c^((k>>4)&31)) + Xl 16K (bf16, swizzled)
// + h_lds 2K + hOut 64B ~= 146 KiB.
// ---------------------------------------------------------------------------

__device__ __forceinline__ float sigf(float x) {
  return 1.0f / (1.0f + __expf(-x));         // v_exp_f32 path, branchless
}
__device__ __forceinline__ float tanh_f(float x) {
  float xx = fminf(15.0f, fmaxf(-15.0f, x)); // exp(2*15) finite, tanh saturated
  float e  = __expf(2.0f * xx);
  return (e - 1.0f) / (e + 1.0f);
}

__device__ __forceinline__ unsigned short f2bf(float x) {
  u32 u = __float_as_uint(x);
  u += 0x7fffu + ((u >> 16) & 1u);
  return (unsigned short)(u >> 16);
}
__device__ __forceinline__ float bf2f(unsigned short s) {
  return __uint_as_float(((u32)s) << 16);
}

// img: u32[2][8][512] = 32KB at ws start (R8 layout)
__global__ void init_ws(u32* w) {
  int i = blockIdx.x * blockDim.x + threadIdx.x;
  if (i < 4096)      w[i] = 0u;   // buf0: tag 0
  else if (i < 8192) w[i] = 1u;   // buf1: tag 1
}

// LDS index swizzles (used consistently by all readers/writers)
__device__ __forceinline__ int wl_idx(int k, int c) { return k * 64 + (c ^ ((k >> 4) & 31)); }
__device__ __forceinline__ int xl_idx(int c, int t) { return c * T_ + (t ^ ((c & 31) << 1)); }

// Stage k-major slice: Wl[k][c] = W[k][(c>>4)*H + s*16 + (c&15)], k < rows
__device__ __forceinline__ void stage_W(const float* __restrict__ W, int rows,
                                        int s, float* __restrict__ Wl) {
  for (int idx = threadIdx.x; idx < rows * 64; idx += NTHR) {
    int k = idx >> 6, c = idx & 63;
    Wl[wl_idx(k, c)] = W[k * G_ + ((c >> 4) * H_ + s * 16 + (c & 15))];
  }
}

__attribute__((amdgpu_waves_per_eu(2)))
__global__ __launch_bounds__(NTHR, 1) void lstm_all(
    const int* __restrict__ tokens, const float* __restrict__ embed,
    const float* __restrict__ Wih_s, const float* __restrict__ Whh_s,
    const float* __restrict__ b_s,
    const float* __restrict__ Wih_t, const float* __restrict__ Whh_t,
    const float* __restrict__ Wmh_t, const float* __restrict__ b_t,
    float* __restrict__ out, u32* __restrict__ img) {
  __shared__ float Wl[H_ * 64];            // 128 KiB, k-major weight slice (swizzled)
  __shared__ unsigned short Xl[64 * T_];   // 16 KiB, bf16 X (swizzled)
  __shared__ float h_lds[H_];              // 2 KiB, staged h (single buffer, 2-barrier safe)
  __shared__ float hOut[16];               // this slot's 16 new h values

  const int tid = threadIdx.x;
  const int l   = tid & 63;                // lane
  const int wv  = tid >> 6;                // wave: owns h-cols {2wv, 2wv+1} (local)
  const int b   = blockIdx.x & 7;          // ring = batch (guaranteed coverage)
  const int s   = blockIdx.x >> 3;         // slot: h-cols 16s..16s+15
  const int kch = l >> 3;                  // k-chunk 0..7 (64 k each)
  const int cc  = ((l & 7) >> 1) * 16 + 2 * wv + (l & 1);  // this lane's gate col
  const int d   = l & 1;                   // h-col parity within wave
  const int bH  = b * H_;

  int wd = 1 << 20;                        // watchdog: poll retries/thread
  float wreg[64];                          // pinned per-lane weight K-slice

  // ---- X phase: Xl[c][t] (bf16) = emb[b,t] @ Wih[:,col(c)] + bias[col(c)]
  auto computeX = [&](const float* __restrict__ Wih, const float* __restrict__ bias) {
    stage_W(Wih, E_, s, Wl);               // 256x64 into Wl (fits)
    __syncthreads();
    const int t = tid >> 2, grp = tid & 3; // grp = gate; 16 cols each
    const int tok = tokens[b * T_ + t];
    const float4* er = (const float4*)(embed + (size_t)tok * E_);
    float acc[16];
#pragma unroll
    for (int j = 0; j < 16; ++j) acc[j] = bias[grp * H_ + s * 16 + j];
    for (int e4 = 0; e4 < E_ / 4; ++e4) {
      float4 em = er[e4];
#pragma unroll
      for (int eo = 0; eo < 4; ++eo) {
        float ev = reinterpret_cast<const float*>(&em)[eo];
        const int k = e4 * 4 + eo;
#pragma unroll
        for (int j = 0; j < 16; ++j) acc[j] += ev * Wl[wl_idx(k, grp * 16 + j)];
      }
    }
#pragma unroll
    for (int j = 0; j < 16; ++j) Xl[xl_idx(grp * 16 + j, t)] = f2bf(acc[j]);
  };

  auto load_wreg = [&] {
#pragma unroll
    for (int kk = 0; kk < 64; ++kk) wreg[kk] = Wl[wl_idx(kch * 64 + kk, cc)];
#pragma unroll
    for (int kk = 0; kk < 64; ++kk) asm volatile("" : "+v"(wreg[kk]));  // pin
  };

  // Per-THREAD poll of OWN float via MALL (R8's proven transport).
  auto poll_own = [&](unsigned gen) {
    const u32 par = (gen >> 1) & 1u;
    const u32* p = img + (gen & 1u) * 4096 + bH + tid;
    u32 u;
    for (;;) {
      u = __hip_atomic_load(p, __ATOMIC_RELAXED, __HIP_MEMORY_SCOPE_AGENT);
      if ((u & 1u) == par) break;
      if (--wd < 0) break;                 // fail fast, not hang
      __builtin_amdgcn_s_sleep(1);
    }
    h_lds[tid] = __uint_as_float(u);       // tag bit kept (1 ulp, harmless)
  };

  // Full dot for this lane's col over shared h_lds: 64 FMAs on its k-chunk
  // (kch-rotated float4 reads: broadcast within 8-lane groups, <=2-way across
  // groups), then 3 shfl_xor over the 8 chunks. (R14-verified math.)
  auto do_dot = [&]() -> float {
    float a0 = 0.f, a1 = 0.f, a2 = 0.f, a3 = 0.f;
    const float4* h4 = (const float4*)(h_lds + kch * 64);
#pragma unroll
    for (int i = 0; i < 16; ++i) {
      const int q = (i + 2 * kch) & 15;    // rotation de-conflicts banks
      float4 hv = h4[q];
      a0 += hv.x * wreg[q * 4 + 0];
      a1 += hv.y * wreg[q * 4 + 1];
      a2 += hv.z * wreg[q * 4 + 2];
      a3 += hv.w * wreg[q * 4 + 3];
    }
    float sum = (a0 + a1) + (a2 + a3);
    sum += __shfl_xor(sum, 8);
    sum += __shfl_xor(sum, 16);
    sum += __shfl_xor(sum, 32);
    return sum;                            // full pre-dot for col cc, all lanes
  };

  // ---------------- Phase A1 + shared weights
  computeX(Wih_s, b_s);
  __syncthreads();
  stage_W(Whh_s, H_, s, Wl);
  __syncthreads();
  load_wreg();

  float c_reg = 0.f, Mreg = 0.f;

  // ---------------- Phase B: shared LSTM; publishes gens 1..128.
  for (int t = 0; t < T_; ++t) {
    float pre = 0.f;
    if (t > 0) {
      poll_own((unsigned)t);
      __syncthreads();                     // barrier 1: h_lds complete
      pre = do_dot();
    }
    if (l < 8) pre += bf2f(Xl[xl_idx(cc, t)]);   // only shfl sources need X
    float gi = __shfl(pre, d),     gf = __shfl(pre, 2 + d),
          gg = __shfl(pre, 4 + d), go = __shfl(pre, 6 + d);
    float cn = sigf(gf) * c_reg + sigf(gi) * tanh_f(gg);
    float hn = sigf(go) * tanh_f(cn);
    c_reg = cn;
    if (l < 2) hOut[2 * wv + l] = hn;      // wave owns h-cols s*16+2wv+{0,1}
    __syncthreads();                       // barrier 2: hOut complete
    if (tid < 16) {                        // SINGLE 16-lane 64B publish (R8 rule)
      const unsigned gw = (unsigned)t + 1u;
      u32 hb = (__float_as_uint(hOut[tid]) & ~1u) | ((gw >> 1) & 1u);
      __hip_atomic_store(img + (gw & 1u) * 4096 + bH + s * 16 + tid, hb,
                         __ATOMIC_RELAXED, __HIP_MEMORY_SCOPE_AGENT);
    }
  }

  // ---------------- M = h_last @ Wmh_t (consume gen 128)
  __syncthreads();
  stage_W(Wmh_t, H_, s, Wl);
  __syncthreads();
  load_wreg();
  poll_own(128u);
  __syncthreads();
  Mreg = do_dot();                         // M for col cc (consistent replicas)

  // ---------------- Phase A2 + task weights
  __syncthreads();
  computeX(Wih_t, b_t);
  __syncthreads();
  stage_W(Whh_t, H_, s, Wl);
  __syncthreads();
  load_wreg();

  // ---------------- Phase C: task LSTM; gens 129..255; out every step
  c_reg = 0.f;
  for (int t = 0; t < T_; ++t) {
    float pre = 0.f;
    if (t > 0) {
      poll_own(128u + (unsigned)t);
      __syncthreads();                     // barrier 1
      pre = do_dot();
    }
    if (l < 8) pre += bf2f(Xl[xl_idx(cc, t)]) + Mreg;
    float gi = __shfl(pre, d),     gf = __shfl(pre, 2 + d),
          gg = __shfl(pre, 4 + d), go = __shfl(pre, 6 + d);
    float cn = sigf(gf) * c_reg + sigf(gi) * tanh_f(gg);
    float hn = sigf(go) * tanh_f(cn);
    c_reg = cn;
    if (l < 2) hOut[2 * wv + l] = hn;
    __syncthreads();                       // barrier 2
    if (tid < 16) {
      out[b * (T_ * H_) + t * H_ + s * 16 + tid] = hOut[tid];  // 64B coalesced
      if (t < T_ - 1) {
        const unsigned gw = 129u + (unsigned)t;
        u32 hb = (__float_as_uint(hOut[tid]) & ~1u) | ((gw >> 1) & 1u);
        __hip_atomic_store(img + (gw & 1u) * 4096 + bH + s * 16 + tid, hb,
                           __ATOMIC_RELAXED, __HIP_MEMORY_SCOPE_AGENT);
      }
    }
  }
}

extern "C" void kernel_launch(void* const* d_in, const int* in_sizes, int n_in,
                              void* d_out, int out_size, void* d_ws, size_t ws_size,
                              hipStream_t stream) {
  const int*   tokens = (const int*)d_in[0];
  // d_in[1] = TASK (unused)
  const float* embed  = (const float*)d_in[2];
  const float* Wih_s  = (const float*)d_in[3];
  const float* Whh_s  = (const float*)d_in[4];
  const float* b_s    = (const float*)d_in[5];
  // d_in[6..9] = Ws_w, Ws_b, Us_w, Us_b -> dead (attention collapses)
  const float* Wih_t  = (const float*)d_in[10];
  const float* Whh_t  = (const float*)d_in[11];
  const float* Wmh_t  = (const float*)d_in[12];
  const float* b_t    = (const float*)d_in[13];
  float* out = (float*)d_out;
  u32*   img = (u32*)d_ws;

  hipLaunchKernelGGL(init_ws, dim3(8), dim3(1024), 0, stream, img);
  hipLaunchKernelGGL(lstm_all, dim3(NWG), dim3(NTHR), 0, stream,
                     tokens, embed, Wih_s, Whh_s, b_s,
                     Wih_t, Whh_t, Wmh_t, b_t, out, img);
}